// Round 4
// baseline (84.495 us; speedup 1.0000x reference)
//
#include <hip/hip_runtime.h>
#include <math.h>

#define VOCAB 100000
#define DIM 128
#define BATCH 4096
#define CTX 20
#define NEGS 10
#define NTARG (CTX + CTX * NEGS)   // 220

__device__ __forceinline__ float log_sigmoid(float x) {
    // numerically stable: min(x,0) - log1p(exp(-|x|))
    float ax = fabsf(x);
    return fminf(x, 0.0f) - log1pf(expf(-ax));
}

__global__ __launch_bounds__(256) void sgns_loss_kernel(
    const int*   __restrict__ i_words,   // [1, B] -> flat [B]
    const int*   __restrict__ o_words,   // [C, B]
    const int*   __restrict__ n_words,   // [B, C*NEG]
    const float* __restrict__ W_i,       // [VOCAB, DIM]
    const float* __restrict__ W_os,      // [VOCAB, DIM]
    float*       __restrict__ out)       // scalar
{
    const int lane = threadIdx.x & 63;
    const int wave = threadIdx.x >> 6;
    const int b    = blockIdx.x * 4 + wave;   // 1024 blocks * 4 waves = 4096 = BATCH

    const int sub = lane >> 4;    // which of 4 concurrent targets
    const int t   = lane & 15;    // position within 16-lane group

    float acc = 0.0f;

    if (b < BATCH) {
        const int ic = i_words[b];
        const float4* iv = (const float4*)(W_i + (size_t)ic * DIM);
        // lane t covers dims [8t, 8t+8)
        float4 i0 = iv[2 * t];
        float4 i1 = iv[2 * t + 1];

        for (int j0 = 0; j0 < NTARG; j0 += 4) {
            int jj = j0 + sub;
            int idx;
            float sgn, w;
            if (jj < CTX) {               // positive target (wave-uniform branch: CTX%4==0)
                idx = o_words[jj * BATCH + b];
                sgn = 1.0f;  w = 1.0f / CTX;
            } else {                      // negative target
                idx = n_words[(size_t)b * (CTX * NEGS) + (jj - CTX)];
                sgn = -1.0f; w = 1.0f / NEGS;
            }
            const float4* ov = (const float4*)(W_os + (size_t)idx * DIM);
            float4 o0 = ov[2 * t];
            float4 o1 = ov[2 * t + 1];

            float p = i0.x * o0.x + i0.y * o0.y + i0.z * o0.z + i0.w * o0.w
                    + i1.x * o1.x + i1.y * o1.y + i1.z * o1.z + i1.w * o1.w;

            // butterfly reduce across the 16-lane group
            p += __shfl_xor(p, 1);
            p += __shfl_xor(p, 2);
            p += __shfl_xor(p, 4);
            p += __shfl_xor(p, 8);

            float term = w * log_sigmoid(sgn * p);
            acc += (t == 0) ? term : 0.0f;
        }
    }

    // wave reduce: nonzero acc lives on lanes 0,16,32,48
    acc += __shfl_xor(acc, 16);
    acc += __shfl_xor(acc, 32);

    __shared__ float ws[4];
    if (lane == 0) ws[wave] = acc;
    __syncthreads();
    if (threadIdx.x == 0) {
        float s = ws[0] + ws[1] + ws[2] + ws[3];
        atomicAdd(out, -s);   // reference returns -loss
    }
}

extern "C" void kernel_launch(void* const* d_in, const int* in_sizes, int n_in,
                              void* d_out, int out_size, void* d_ws, size_t ws_size,
                              hipStream_t stream) {
    const int*   i_words = (const int*)d_in[0];
    const int*   o_words = (const int*)d_in[1];
    const int*   n_words = (const int*)d_in[2];
    const float* W_i     = (const float*)d_in[3];
    const float* W_os    = (const float*)d_in[4];
    float* out = (float*)d_out;

    hipMemsetAsync(out, 0, sizeof(float), stream);
    sgns_loss_kernel<<<1024, 256, 0, stream>>>(i_words, o_words, n_words, W_i, W_os, out);
}